// Round 2
// 1736.245 us; speedup vs baseline: 1.1266x; 1.1266x over previous
//
#include <hip/hip_runtime.h>
#include <hip/hip_bf16.h>
#include <stdint.h>

typedef __bf16 bf16x8 __attribute__((ext_vector_type(8)));
typedef float floatx4 __attribute__((ext_vector_type(4)));

__device__ __forceinline__ float bf2f(__hip_bfloat16 v) { return __bfloat162float(v); }
__device__ __forceinline__ __hip_bfloat16 f2bf(float v) { return __float2bfloat16(v); }

#define WKV_CH 64   // chunk length for the scan decomposition

// ---------------- elementwise: fp32 -> bf16 cast ----------------
__global__ __launch_bounds__(256) void k_f2bf(const float* __restrict__ in,
                                              __hip_bfloat16* __restrict__ out, int n) {
    int i = blockIdx.x * 256 + threadIdx.x;
    if (i < n) out[i] = f2bf(in[i]);
}

// ---------------- LayerNorm: one block per row, bf16 out ----------------
__global__ __launch_bounds__(256) void k_ln(const float* __restrict__ x,
                                            const float* __restrict__ w,
                                            const float* __restrict__ b,
                                            __hip_bfloat16* __restrict__ out, int d) {
    __shared__ float red[8];
    const size_t row = blockIdx.x;
    const float* xr = x + row * (size_t)d;
    float s = 0.f, ss = 0.f;
    for (int i = threadIdx.x; i < d; i += 256) {
        float v = xr[i];
        s += v; ss += v * v;
    }
    for (int off = 32; off > 0; off >>= 1) {
        s  += __shfl_down(s,  off, 64);
        ss += __shfl_down(ss, off, 64);
    }
    int wv = threadIdx.x >> 6, ln = threadIdx.x & 63;
    if (ln == 0) { red[wv] = s; red[4 + wv] = ss; }
    __syncthreads();
    s  = red[0] + red[1] + red[2] + red[3];
    ss = red[4] + red[5] + red[6] + red[7];
    float mu  = s / d;
    float var = ss / d - mu * mu;
    float rs  = rsqrtf(var + 1e-5f);
    __hip_bfloat16* orow = out + row * (size_t)d;
    for (int i = threadIdx.x; i < d; i += 256) {
        orow[i] = f2bf((xr[i] - mu) * rs * w[i] + b[i]);
    }
}

// ---------------- time-mix prep (shift + mix + sigmoid on r) ----------------
__global__ __launch_bounds__(256) void k_tmix(const __hip_bfloat16* __restrict__ xln,
    const float* __restrict__ mk, const float* __restrict__ mv, const float* __restrict__ mr,
    __hip_bfloat16* __restrict__ xk, __hip_bfloat16* __restrict__ xv, __hip_bfloat16* __restrict__ xr,
    int T, int d) {
    const int c = blockIdx.x * 256 + threadIdx.x;
    const size_t row = blockIdx.y;
    const int t = (int)(row % (size_t)T);
    const size_t idx = row * (size_t)d + c;
    float xc = bf2f(xln[idx]);
    float xs = t ? bf2f(xln[idx - d]) : 0.f;
    float a = mk[c];
    xk[idx] = f2bf(xc * a + xs * (1.f - a));
    float bq = mv[c];
    xv[idx] = f2bf(xc * bq + xs * (1.f - bq));
    float rm = mr[c];
    float pre = xc * rm + xs * (1.f - rm);
    xr[idx] = f2bf(1.f / (1.f + __expf(-pre)));   // sigmoid BEFORE Wr gemm (per reference)
}

// ---------------- channel-mix prep ----------------
__global__ __launch_bounds__(256) void k_cmix(const __hip_bfloat16* __restrict__ xln,
    const float* __restrict__ mk, const float* __restrict__ mr,
    __hip_bfloat16* __restrict__ xk, __hip_bfloat16* __restrict__ xr,
    int T, int d) {
    const int c = blockIdx.x * 256 + threadIdx.x;
    const size_t row = blockIdx.y;
    const int t = (int)(row % (size_t)T);
    const size_t idx = row * (size_t)d + c;
    float xc = bf2f(xln[idx]);
    float xs = t ? bf2f(xln[idx - d]) : 0.f;
    float a = mk[c];
    xk[idx] = f2bf(xc * a + xs * (1.f - a));
    float rm = mr[c];
    xr[idx] = f2bf(xc * rm + xs * (1.f - rm));
}

// ---------------- WKV chunked scan ----------------
__global__ __launch_bounds__(256) void k_wkv_p1(const __hip_bfloat16* __restrict__ k,
    const __hip_bfloat16* __restrict__ v,
    const float* __restrict__ u, const float* __restrict__ w,
    float* __restrict__ Ac, float* __restrict__ Bc, float* __restrict__ Pc,
    int T, int d, int nch) {
    const int idx = blockIdx.x * 256 + threadIdx.x;
    const int c = idx & (d - 1);
    const int rest = idx / d;
    const int j = rest & (nch - 1);
    const int b = rest / nch;
    const float uc = u[c], wc = w[c];
    float aa = 0.f, bb = 0.f, P = 0.f;
    const size_t base = ((size_t)b * T + (size_t)j * WKV_CH) * d + c;
#pragma unroll 4
    for (int t = 0; t < WKV_CH; ++t) {
        float kt = bf2f(k[base + (size_t)t * d]);
        float vt = bf2f(v[base + (size_t)t * d]);
        float q  = fmaxf(uc + kt, wc);
        float e1 = __expf(-wc - q);
        float e2 = __expf(uc + kt - q);
        aa = e1 * aa + e2 * vt;
        bb = e1 * bb + e2;
        P += wc + q;
    }
    const size_t s = ((size_t)b * nch + j) * d + c;
    Ac[s] = aa; Bc[s] = bb; Pc[s] = P;
}

__global__ __launch_bounds__(256) void k_wkv_p2(const float* __restrict__ Ac,
    const float* __restrict__ Bc, const float* __restrict__ Pc,
    float* __restrict__ Ain, float* __restrict__ Bin, int d, int nch) {
    const int idx = blockIdx.x * 256 + threadIdx.x;   // b*d + c
    const int c = idx & (d - 1);
    const int b = idx / d;
    float a = 0.f, bbs = 0.f;
    for (int j = 0; j < nch; ++j) {
        const size_t s = ((size_t)b * nch + j) * d + c;
        Ain[s] = a; Bin[s] = bbs;
        float p = __expf(-Pc[s]);
        a   = p * a   + Ac[s];
        bbs = p * bbs + Bc[s];
    }
}

__global__ __launch_bounds__(256) void k_wkv_p3(const __hip_bfloat16* __restrict__ k,
    const __hip_bfloat16* v,
    const __hip_bfloat16* __restrict__ r,
    const float* __restrict__ u, const float* __restrict__ w,
    const float* __restrict__ Ain, const float* __restrict__ Bin,
    __hip_bfloat16* out, int T, int d, int nch) {
    const int idx = blockIdx.x * 256 + threadIdx.x;
    const int c = idx & (d - 1);
    const int rest = idx / d;
    const int j = rest & (nch - 1);
    const int b = rest / nch;
    const float uc = u[c], wc = w[c];
    const size_t s = ((size_t)b * nch + j) * d + c;
    float aa = Ain[s], bb = Bin[s];
    const size_t base = ((size_t)b * T + (size_t)j * WKV_CH) * d + c;
#pragma unroll 4
    for (int t = 0; t < WKV_CH; ++t) {
        float kt = bf2f(k[base + (size_t)t * d]);
        float vt = bf2f(v[base + (size_t)t * d]);
        float rt = bf2f(r[base + (size_t)t * d]);
        float q  = fmaxf(uc + kt, wc);
        float e1 = __expf(-wc - q);
        float e2 = __expf(uc + kt - q);
        aa = e1 * aa + e2 * vt;
        bb = e1 * bb + e2;
        out[base + (size_t)t * d] = f2bf((aa / bb) * rt);
    }
}

// ---------------- bf16 MFMA GEMM: C[M,N] = A[M,K] @ B[N,K]^T ----------------
// 256x256 tile, BK=64, 8 waves (2Mx4N), 128 KiB static LDS double-buffer.
// 8-phase schedule: counted vmcnt(6) once per K-tile (tail drains to 0),
// stagger-7 half-tile staging stream. LDS XOR-swizzle via pre-swizzled
// global source + swizzled ds_read (global_load_lds dest stays linear).
// sched_barrier(0) pins at every s_barrier (m152/rule-18: raw s_barrier is
// not a compiler fence). setprio around MFMA clusters.
#define GM_BF16  0
#define GM_ADDX  1
#define GM_SIG   2
#define GM_RELU2 3
#define GM_FINAL 4

// region -> LDS offset within a 64 KiB buffer (compile-time).
// Staging order per K-tile: 0:A-lo(+0) 1:B-lo(+32K) 2:A-hi(+16K) 3:B-hi(+48K)
#define REGLDS(reg) ((unsigned)((reg) == 0 ? 0u : (reg) == 1 ? 32768u : (reg) == 2 ? 16384u : 49152u))
#define SBAR() __builtin_amdgcn_sched_barrier(0)

template<int MODE>
__global__ __launch_bounds__(512, 2)
void gemm_bt(const __hip_bfloat16* __restrict__ A,
             const __hip_bfloat16* __restrict__ B,
             void* __restrict__ outv,
             const float* __restrict__ auxf,
             const float* __restrict__ bias,
             const __hip_bfloat16* __restrict__ auxb,
             int N, int K) {
    __shared__ char smem[131072];
    const int tid  = threadIdx.x;
    const int lane = tid & 63;
    const int wave = tid >> 6;
    const int wm = wave >> 2;          // 0..1
    const int wn = wave & 3;           // 0..3
    const int NT = K >> 6;             // K-tiles of 64
    const size_t Kb = (size_t)K * 2;   // row stride in bytes

    const int bn = blockIdx.x * 256;   // gx=8 -> default dispatch already gives
    const int bm = blockIdx.y * 256;   // per-XCD B-panel locality (bid%8 = bx)

    // ---- staging: per-lane pre-swizzled global source ----
    // LDS chunk g = q*512 + tid ; row = g>>3 ; ci = g&7 ; src k-chunk = ci ^ (row&7)
    const int rh0 = tid >> 3;                              // 0..63 (q adds 64)
    const int kc8 = ((tid & 7) ^ (rh0 & 7)) << 3;          // element offset, q-invariant
    const size_t offA = ((size_t)(bm + rh0) * K + kc8) * 2;
    const size_t offB = ((size_t)(bn + rh0) * K + kc8) * 2;
    const unsigned waveBase = (unsigned)(wave * 64);

#define STAGE(tau, reg) do {                                                        \
    int _tt = (tau);                                                                \
    if (_tt < NT) {                                                                 \
        const char* _gp = ((reg) & 1) ? (const char*)B : (const char*)A;            \
        size_t _go = (((reg) & 1) ? offB : offA)                                    \
                   + (((reg) >= 2) ? (size_t)128 * Kb : 0) + (size_t)_tt * 128;     \
        unsigned _lb = ((unsigned)(_tt & 1) << 16) + REGLDS(reg);                   \
        _Pragma("unroll")                                                           \
        for (int _q = 0; _q < 2; ++_q) {                                            \
            __builtin_amdgcn_global_load_lds(                                       \
                (__attribute__((address_space(1))) void*)(_gp + _go + (size_t)_q * 64 * Kb), \
                (__attribute__((address_space(3))) void*)(smem + _lb + (unsigned)(_q * 512 + waveBase) * 16), \
                16, 0, 0);                                                          \
        }                                                                           \
    }                                                                               \
} while (0)

    // ---- fragment-read per-lane offsets (swizzled) ----
    const int lane15 = lane & 15;
    const int laneHi = lane >> 4;
    const int chunk0 = ((laneHi)     ^ (lane & 7)) << 4;   // k-slice s=0
    const int chunk1 = ((laneHi + 4) ^ (lane & 7)) << 4;   // k-slice s=1
    const int aLane = (wm * 64 + lane15) * 128;            // within A (+mh*16384 +i*2048)
    const int bLane = 32768 + (wn * 32 + lane15) * 128;    // within B (+nh*16384 +jf*2048)

    floatx4 acc00[4][2] = {}, acc01[4][2] = {}, acc11[4][2] = {}, acc10[4][2] = {};
    bf16x8 a[4][2], b0[2][2], b1[2][2];

    // ---- prologue: stage tile0 fully + tile1 regions 0..2 (7 half-tiles),
    //      drain the 8 oldest (= all of tile0) ----
    STAGE(0, 0); STAGE(0, 1); STAGE(0, 2); STAGE(0, 3);
    STAGE(1, 0); STAGE(1, 1); STAGE(1, 2);
    asm volatile("s_waitcnt vmcnt(6)" ::: "memory");
    SBAR(); __builtin_amdgcn_s_barrier(); SBAR();

#pragma unroll 2
    for (int t = 0; t < NT; ++t) {
        const char* sA = smem + ((t & 1) << 16) + aLane;
        const char* sB = smem + ((t & 1) << 16) + bLane;

        // -------- phase 0: quadrant (mh=0, nh=0); stage B-hi of t+1 --------
#pragma unroll
        for (int i = 0; i < 4; ++i) {
            a[i][0] = *(const bf16x8*)(sA + i * 2048 + chunk0);
            a[i][1] = *(const bf16x8*)(sA + i * 2048 + chunk1);
        }
#pragma unroll
        for (int j = 0; j < 2; ++j) {
            b0[j][0] = *(const bf16x8*)(sB + j * 2048 + chunk0);
            b0[j][1] = *(const bf16x8*)(sB + j * 2048 + chunk1);
        }
        STAGE(t + 1, 3);
        SBAR(); __builtin_amdgcn_s_barrier(); SBAR();
        __builtin_amdgcn_s_setprio(1);
#pragma unroll
        for (int i = 0; i < 4; ++i)
#pragma unroll
            for (int j = 0; j < 2; ++j) {
                acc00[i][j] = __builtin_amdgcn_mfma_f32_16x16x32_bf16(a[i][0], b0[j][0], acc00[i][j], 0, 0, 0);
                acc00[i][j] = __builtin_amdgcn_mfma_f32_16x16x32_bf16(a[i][1], b0[j][1], acc00[i][j], 0, 0, 0);
            }
        __builtin_amdgcn_s_setprio(0);
        SBAR(); __builtin_amdgcn_s_barrier(); SBAR();

        // -------- phase 1: quadrant (0,1); stage A-lo of t+2 --------
#pragma unroll
        for (int j = 0; j < 2; ++j) {
            b1[j][0] = *(const bf16x8*)(sB + 16384 + j * 2048 + chunk0);
            b1[j][1] = *(const bf16x8*)(sB + 16384 + j * 2048 + chunk1);
        }
        STAGE(t + 2, 0);
        SBAR(); __builtin_amdgcn_s_barrier(); SBAR();
        __builtin_amdgcn_s_setprio(1);
#pragma unroll
        for (int i = 0; i < 4; ++i)
#pragma unroll
            for (int j = 0; j < 2; ++j) {
                acc01[i][j] = __builtin_amdgcn_mfma_f32_16x16x32_bf16(a[i][0], b1[j][0], acc01[i][j], 0, 0, 0);
                acc01[i][j] = __builtin_amdgcn_mfma_f32_16x16x32_bf16(a[i][1], b1[j][1], acc01[i][j], 0, 0, 0);
            }
        __builtin_amdgcn_s_setprio(0);
        SBAR(); __builtin_amdgcn_s_barrier(); SBAR();

        // -------- phase 2: quadrant (1,1); stage B-lo of t+2 --------
#pragma unroll
        for (int i = 0; i < 4; ++i) {
            a[i][0] = *(const bf16x8*)(sA + 16384 + i * 2048 + chunk0);
            a[i][1] = *(const bf16x8*)(sA + 16384 + i * 2048 + chunk1);
        }
        STAGE(t + 2, 1);
        SBAR(); __builtin_amdgcn_s_barrier(); SBAR();
        __builtin_amdgcn_s_setprio(1);
#pragma unroll
        for (int i = 0; i < 4; ++i)
#pragma unroll
            for (int j = 0; j < 2; ++j) {
                acc11[i][j] = __builtin_amdgcn_mfma_f32_16x16x32_bf16(a[i][0], b1[j][0], acc11[i][j], 0, 0, 0);
                acc11[i][j] = __builtin_amdgcn_mfma_f32_16x16x32_bf16(a[i][1], b1[j][1], acc11[i][j], 0, 0, 0);
            }
        __builtin_amdgcn_s_setprio(0);
        SBAR(); __builtin_amdgcn_s_barrier(); SBAR();

        // -------- phase 3: quadrant (1,0); stage A-hi of t+2; tile-boundary drain --------
        STAGE(t + 2, 2);
        SBAR(); __builtin_amdgcn_s_barrier(); SBAR();
        __builtin_amdgcn_s_setprio(1);
#pragma unroll
        for (int i = 0; i < 4; ++i)
#pragma unroll
            for (int j = 0; j < 2; ++j) {
                acc10[i][j] = __builtin_amdgcn_mfma_f32_16x16x32_bf16(a[i][0], b0[j][0], acc10[i][j], 0, 0, 0);
                acc10[i][j] = __builtin_amdgcn_mfma_f32_16x16x32_bf16(a[i][1], b0[j][1], acc10[i][j], 0, 0, 0);
            }
        __builtin_amdgcn_s_setprio(0);
        SBAR();
        // steady state: 14 outstanding, drain 8 oldest (= all of tile t+1).
        // tail (t+2 >= NT): the t+2 stages were skipped -> must drain fully,
        // else tile t+1's regions r1..r3 are still in flight when read.
        if (t + 2 < NT) {
            asm volatile("s_waitcnt vmcnt(6)" ::: "memory");
        } else {
            asm volatile("s_waitcnt vmcnt(0)" ::: "memory");
        }
        __builtin_amdgcn_s_barrier(); SBAR();
    }
#undef STAGE

    // ---- epilogue ----
    const int erow = bm + wm * 64 + (laneHi << 2);
    const int ecol = bn + wn * 32 + lane15;
#define EPI(ACC, MH, NH)                                                            \
    _Pragma("unroll")                                                               \
    for (int i = 0; i < 4; ++i) {                                                   \
        _Pragma("unroll")                                                           \
        for (int jf = 0; jf < 2; ++jf) {                                            \
            const int c = ecol + (NH) * 128 + jf * 16;                              \
            _Pragma("unroll")                                                       \
            for (int j = 0; j < 4; ++j) {                                           \
                const int r = erow + (MH) * 128 + i * 16 + j;                       \
                const size_t idx = (size_t)r * N + c;                               \
                const float val = ACC[i][jf][j];                                    \
                if (MODE == GM_BF16) {                                              \
                    ((__hip_bfloat16*)outv)[idx] = f2bf(val);                       \
                } else if (MODE == GM_ADDX) {                                       \
                    ((float*)outv)[idx] = auxf[idx] + bias[c] + val;                \
                } else if (MODE == GM_SIG) {                                        \
                    ((__hip_bfloat16*)outv)[idx] = f2bf(1.f / (1.f + __expf(-val))); \
                } else if (MODE == GM_RELU2) {                                      \
                    float tp = fmaxf(val, 0.f);                                     \
                    ((__hip_bfloat16*)outv)[idx] = f2bf(tp * tp);                   \
                } else {                                                            \
                    float* o = (float*)outv;                                        \
                    o[idx] = o[idx] + bf2f(auxb[idx]) * val;                        \
                }                                                                   \
            }                                                                       \
        }                                                                           \
    }
    EPI(acc00, 0, 0)
    EPI(acc01, 0, 1)
    EPI(acc11, 1, 1)
    EPI(acc10, 1, 0)
#undef EPI
}

// ---------------- launch ----------------
extern "C" void kernel_launch(void* const* d_in, const int* in_sizes, int n_in,
                              void* d_out, int out_size, void* d_ws, size_t ws_size,
                              hipStream_t stream) {
    const float* x      = (const float*)d_in[0];
    const float* ln1_w  = (const float*)d_in[1];
    const float* ln1_b  = (const float*)d_in[2];
    const float* ln2_w  = (const float*)d_in[3];
    const float* ln2_b  = (const float*)d_in[4];
    const float* tm_u   = (const float*)d_in[5];
    const float* tm_w   = (const float*)d_in[6];
    const float* tm_mk  = (const float*)d_in[7];
    const float* tm_mv  = (const float*)d_in[8];
    const float* tm_mr  = (const float*)d_in[9];
    const float* tm_bo  = (const float*)d_in[14];
    const float* cm_mk  = (const float*)d_in[15];
    const float* cm_mr  = (const float*)d_in[16];

    const int D = in_sizes[1];           // 2048
    const int Mrows = in_sizes[0] / D;   // 16384
    const int T = 2048;
    const int Bb = Mrows / T;            // 8
    const size_t dd = (size_t)D * D;
    const size_t md = (size_t)Mrows * D;
    const int nch = T / WKV_CH;          // 32

    __hip_bfloat16* W = (__hip_bfloat16*)d_ws;
    __hip_bfloat16* buf[7];
    for (int i = 0; i < 7; ++i) buf[i] = W + 7 * dd + (size_t)i * md;
    // buf0: xln -> (scan scratch) -> x2ln ; buf1: xk -> xk2 ; buf2: xv -> xr2
    // buf3: xr -> r2s ; buf4: k ; buf5: v -> wkv*r ; buf6: r -> k2

    float* S = (float*)buf[0];
    const size_t cs = (size_t)Bb * nch * D;   // 524288 floats = 2 MB
    float* Ac  = S;
    float* Bc  = S + cs;
    float* Pc  = S + 2 * cs;
    float* Ain = S + 3 * cs;
    float* Bin = S + 4 * cs;

    const int widx[7] = {10, 11, 12, 13, 17, 18, 19};
    for (int i = 0; i < 7; ++i)
        k_f2bf<<<(int)(dd / 256), 256, 0, stream>>>((const float*)d_in[widx[i]], W + (size_t)i * dd, (int)dd);

    k_ln<<<Mrows, 256, 0, stream>>>(x, ln1_w, ln1_b, buf[0], D);
    k_tmix<<<dim3(D / 256, Mrows), 256, 0, stream>>>(buf[0], tm_mk, tm_mv, tm_mr,
                                                     buf[1], buf[2], buf[3], T, D);
    dim3 gg(D / 256, Mrows / 256);
    gemm_bt<GM_BF16><<<gg, 512, 0, stream>>>(buf[1], W + 0 * dd, buf[4], nullptr, nullptr, nullptr, D, D);
    gemm_bt<GM_BF16><<<gg, 512, 0, stream>>>(buf[2], W + 1 * dd, buf[5], nullptr, nullptr, nullptr, D, D);
    gemm_bt<GM_BF16><<<gg, 512, 0, stream>>>(buf[3], W + 2 * dd, buf[6], nullptr, nullptr, nullptr, D, D);

    k_wkv_p1<<<(Bb * D * nch) / 256, 256, 0, stream>>>(buf[4], buf[5], tm_u, tm_w,
                                                       Ac, Bc, Pc, T, D, nch);
    k_wkv_p2<<<(Bb * D) / 256, 256, 0, stream>>>(Ac, Bc, Pc, Ain, Bin, D, nch);
    k_wkv_p3<<<(Bb * D * nch) / 256, 256, 0, stream>>>(buf[4], buf[5], buf[6], tm_u, tm_w,
                                                       Ain, Bin, buf[5], T, D, nch);

    gemm_bt<GM_ADDX><<<gg, 512, 0, stream>>>(buf[5], W + 3 * dd, d_out, x, tm_bo, nullptr, D, D);
    k_ln<<<Mrows, 256, 0, stream>>>((const float*)d_out, ln2_w, ln2_b, buf[0], D);
    k_cmix<<<dim3(D / 256, Mrows), 256, 0, stream>>>(buf[0], cm_mk, cm_mr, buf[1], buf[2], T, D);
    gemm_bt<GM_SIG><<<gg, 512, 0, stream>>>(buf[2], W + 6 * dd, buf[3], nullptr, nullptr, nullptr, D, D);
    gemm_bt<GM_RELU2><<<gg, 512, 0, stream>>>(buf[1], W + 4 * dd, buf[6], nullptr, nullptr, nullptr, D, D);
    gemm_bt<GM_FINAL><<<gg, 512, 0, stream>>>(buf[6], W + 5 * dd, d_out, nullptr, nullptr, buf[3], D, D);
}

// Round 3
// 1719.784 us; speedup vs baseline: 1.1374x; 1.0096x over previous
//
#include <hip/hip_runtime.h>
#include <hip/hip_bf16.h>
#include <stdint.h>

typedef __bf16 bf16x8 __attribute__((ext_vector_type(8)));
typedef float floatx4 __attribute__((ext_vector_type(4)));

__device__ __forceinline__ float bf2f(__hip_bfloat16 v) { return __bfloat162float(v); }
__device__ __forceinline__ __hip_bfloat16 f2bf(float v) { return __float2bfloat16(v); }

#define WKV_CH 64   // chunk length for the scan decomposition

// ---------------- elementwise: fp32 -> bf16 cast ----------------
__global__ __launch_bounds__(256) void k_f2bf(const float* __restrict__ in,
                                              __hip_bfloat16* __restrict__ out, int n) {
    int i = blockIdx.x * 256 + threadIdx.x;
    if (i < n) out[i] = f2bf(in[i]);
}

// ---------------- LayerNorm: one block per row, bf16 out ----------------
__global__ __launch_bounds__(256) void k_ln(const float* __restrict__ x,
                                            const float* __restrict__ w,
                                            const float* __restrict__ b,
                                            __hip_bfloat16* __restrict__ out, int d) {
    __shared__ float red[8];
    const size_t row = blockIdx.x;
    const float* xr = x + row * (size_t)d;
    float s = 0.f, ss = 0.f;
    for (int i = threadIdx.x; i < d; i += 256) {
        float v = xr[i];
        s += v; ss += v * v;
    }
    for (int off = 32; off > 0; off >>= 1) {
        s  += __shfl_down(s,  off, 64);
        ss += __shfl_down(ss, off, 64);
    }
    int wv = threadIdx.x >> 6, ln = threadIdx.x & 63;
    if (ln == 0) { red[wv] = s; red[4 + wv] = ss; }
    __syncthreads();
    s  = red[0] + red[1] + red[2] + red[3];
    ss = red[4] + red[5] + red[6] + red[7];
    float mu  = s / d;
    float var = ss / d - mu * mu;
    float rs  = rsqrtf(var + 1e-5f);
    __hip_bfloat16* orow = out + row * (size_t)d;
    for (int i = threadIdx.x; i < d; i += 256) {
        orow[i] = f2bf((xr[i] - mu) * rs * w[i] + b[i]);
    }
}

// ---------------- time-mix prep (shift + mix + sigmoid on r) ----------------
__global__ __launch_bounds__(256) void k_tmix(const __hip_bfloat16* __restrict__ xln,
    const float* __restrict__ mk, const float* __restrict__ mv, const float* __restrict__ mr,
    __hip_bfloat16* __restrict__ xk, __hip_bfloat16* __restrict__ xv, __hip_bfloat16* __restrict__ xr,
    int T, int d) {
    const int c = blockIdx.x * 256 + threadIdx.x;
    const size_t row = blockIdx.y;
    const int t = (int)(row % (size_t)T);
    const size_t idx = row * (size_t)d + c;
    float xc = bf2f(xln[idx]);
    float xs = t ? bf2f(xln[idx - d]) : 0.f;
    float a = mk[c];
    xk[idx] = f2bf(xc * a + xs * (1.f - a));
    float bq = mv[c];
    xv[idx] = f2bf(xc * bq + xs * (1.f - bq));
    float rm = mr[c];
    float pre = xc * rm + xs * (1.f - rm);
    xr[idx] = f2bf(1.f / (1.f + __expf(-pre)));   // sigmoid BEFORE Wr gemm (per reference)
}

// ---------------- channel-mix prep ----------------
__global__ __launch_bounds__(256) void k_cmix(const __hip_bfloat16* __restrict__ xln,
    const float* __restrict__ mk, const float* __restrict__ mr,
    __hip_bfloat16* __restrict__ xk, __hip_bfloat16* __restrict__ xr,
    int T, int d) {
    const int c = blockIdx.x * 256 + threadIdx.x;
    const size_t row = blockIdx.y;
    const int t = (int)(row % (size_t)T);
    const size_t idx = row * (size_t)d + c;
    float xc = bf2f(xln[idx]);
    float xs = t ? bf2f(xln[idx - d]) : 0.f;
    float a = mk[c];
    xk[idx] = f2bf(xc * a + xs * (1.f - a));
    float rm = mr[c];
    xr[idx] = f2bf(xc * rm + xs * (1.f - rm));
}

// ---------------- WKV chunked scan ----------------
__global__ __launch_bounds__(256) void k_wkv_p1(const __hip_bfloat16* __restrict__ k,
    const __hip_bfloat16* __restrict__ v,
    const float* __restrict__ u, const float* __restrict__ w,
    float* __restrict__ Ac, float* __restrict__ Bc, float* __restrict__ Pc,
    int T, int d, int nch) {
    const int idx = blockIdx.x * 256 + threadIdx.x;
    const int c = idx & (d - 1);
    const int rest = idx / d;
    const int j = rest & (nch - 1);
    const int b = rest / nch;
    const float uc = u[c], wc = w[c];
    float aa = 0.f, bb = 0.f, P = 0.f;
    const size_t base = ((size_t)b * T + (size_t)j * WKV_CH) * d + c;
#pragma unroll 4
    for (int t = 0; t < WKV_CH; ++t) {
        float kt = bf2f(k[base + (size_t)t * d]);
        float vt = bf2f(v[base + (size_t)t * d]);
        float q  = fmaxf(uc + kt, wc);
        float e1 = __expf(-wc - q);
        float e2 = __expf(uc + kt - q);
        aa = e1 * aa + e2 * vt;
        bb = e1 * bb + e2;
        P += wc + q;
    }
    const size_t s = ((size_t)b * nch + j) * d + c;
    Ac[s] = aa; Bc[s] = bb; Pc[s] = P;
}

__global__ __launch_bounds__(256) void k_wkv_p2(const float* __restrict__ Ac,
    const float* __restrict__ Bc, const float* __restrict__ Pc,
    float* __restrict__ Ain, float* __restrict__ Bin, int d, int nch) {
    const int idx = blockIdx.x * 256 + threadIdx.x;   // b*d + c
    const int c = idx & (d - 1);
    const int b = idx / d;
    float a = 0.f, bbs = 0.f;
    for (int j = 0; j < nch; ++j) {
        const size_t s = ((size_t)b * nch + j) * d + c;
        Ain[s] = a; Bin[s] = bbs;
        float p = __expf(-Pc[s]);
        a   = p * a   + Ac[s];
        bbs = p * bbs + Bc[s];
    }
}

__global__ __launch_bounds__(256) void k_wkv_p3(const __hip_bfloat16* __restrict__ k,
    const __hip_bfloat16* v,
    const __hip_bfloat16* __restrict__ r,
    const float* __restrict__ u, const float* __restrict__ w,
    const float* __restrict__ Ain, const float* __restrict__ Bin,
    __hip_bfloat16* out, int T, int d, int nch) {
    const int idx = blockIdx.x * 256 + threadIdx.x;
    const int c = idx & (d - 1);
    const int rest = idx / d;
    const int j = rest & (nch - 1);
    const int b = rest / nch;
    const float uc = u[c], wc = w[c];
    const size_t s = ((size_t)b * nch + j) * d + c;
    float aa = Ain[s], bb = Bin[s];
    const size_t base = ((size_t)b * T + (size_t)j * WKV_CH) * d + c;
#pragma unroll 4
    for (int t = 0; t < WKV_CH; ++t) {
        float kt = bf2f(k[base + (size_t)t * d]);
        float vt = bf2f(v[base + (size_t)t * d]);
        float rt = bf2f(r[base + (size_t)t * d]);
        float q  = fmaxf(uc + kt, wc);
        float e1 = __expf(-wc - q);
        float e2 = __expf(uc + kt - q);
        aa = e1 * aa + e2 * vt;
        bb = e1 * bb + e2;
        out[base + (size_t)t * d] = f2bf((aa / bb) * rt);
    }
}

// ---------------- bf16 MFMA GEMM: C[M,N] = A[M,K] @ B[N,K]^T ----------------
// 256x256 tile, BK=64, 8 waves (2Mx4N), 128 KiB static LDS double-buffer.
// 8-phase schedule: counted vmcnt(6) once per K-tile (tail drains to 0).
// LDS XOR-swizzle via pre-swizzled global source + swizzled ds_read.
// XCD remap (this round): tiles sharing an A-panel (same bm, all bn) are
// placed on the SAME XCD so the A-slab is 1 HBM fetch + 7 L2 hits.
// HW places block bid on XCD bid%8; we give XCD c the tile range
// L in [c*64, c*64+64) with bn-fastest order.
#define GM_BF16  0
#define GM_ADDX  1
#define GM_SIG   2
#define GM_RELU2 3
#define GM_FINAL 4

// region -> LDS offset within a 64 KiB buffer (compile-time).
// Staging order per K-tile: 0:A-lo(+0) 1:B-lo(+32K) 2:A-hi(+16K) 3:B-hi(+48K)
#define REGLDS(reg) ((unsigned)((reg) == 0 ? 0u : (reg) == 1 ? 32768u : (reg) == 2 ? 16384u : 49152u))
#define SBAR() __builtin_amdgcn_sched_barrier(0)

template<int MODE>
__global__ __launch_bounds__(512, 2)
void gemm_bt(const __hip_bfloat16* __restrict__ A,
             const __hip_bfloat16* __restrict__ B,
             void* __restrict__ outv,
             const float* __restrict__ auxf,
             const float* __restrict__ bias,
             const __hip_bfloat16* __restrict__ auxb,
             int N, int K) {
    __shared__ char smem[131072];
    const int tid  = threadIdx.x;
    const int lane = tid & 63;
    const int wave = tid >> 6;
    const int wm = wave >> 2;          // 0..1
    const int wn = wave & 3;           // 0..3
    const int NT = K >> 6;             // K-tiles of 64
    const size_t Kb = (size_t)K * 2;   // row stride in bytes

    // ---- XCD-aware tile remap: same-bm tiles on same XCD (A-panel sharing) ----
    const int gx = gridDim.x, gy = gridDim.y;
    const int nwg = gx * gy;
    int bid = blockIdx.y * gx + blockIdx.x;
    int L = bid;
    if ((nwg & 7) == 0) {
        const int cpx = nwg >> 3;
        L = (bid & 7) * cpx + (bid >> 3);   // XCD c owns L in [c*cpx, (c+1)*cpx)
    }
    const int bn = (L % gx) * 256;          // bn-fastest: A-panel readers co-resident
    const int bm = (L / gx) * 256;

    // ---- staging: per-lane pre-swizzled global source ----
    // LDS chunk g = q*512 + tid ; row = g>>3 ; ci = g&7 ; src k-chunk = ci ^ (row&7)
    const int rh0 = tid >> 3;                              // 0..63 (q adds 64)
    const int kc8 = ((tid & 7) ^ (rh0 & 7)) << 3;          // element offset, q-invariant
    const size_t offA = ((size_t)(bm + rh0) * K + kc8) * 2;
    const size_t offB = ((size_t)(bn + rh0) * K + kc8) * 2;
    const unsigned waveBase = (unsigned)(wave * 64);

#define STAGE(tau, reg) do {                                                        \
    int _tt = (tau);                                                                \
    if (_tt < NT) {                                                                 \
        const char* _gp = ((reg) & 1) ? (const char*)B : (const char*)A;            \
        size_t _go = (((reg) & 1) ? offB : offA)                                    \
                   + (((reg) >= 2) ? (size_t)128 * Kb : 0) + (size_t)_tt * 128;     \
        unsigned _lb = ((unsigned)(_tt & 1) << 16) + REGLDS(reg);                   \
        _Pragma("unroll")                                                           \
        for (int _q = 0; _q < 2; ++_q) {                                            \
            __builtin_amdgcn_global_load_lds(                                       \
                (__attribute__((address_space(1))) void*)(_gp + _go + (size_t)_q * 64 * Kb), \
                (__attribute__((address_space(3))) void*)(smem + _lb + (unsigned)(_q * 512 + waveBase) * 16), \
                16, 0, 0);                                                          \
        }                                                                           \
    }                                                                               \
} while (0)

    // ---- fragment-read per-lane offsets (swizzled) ----
    const int lane15 = lane & 15;
    const int laneHi = lane >> 4;
    const int chunk0 = ((laneHi)     ^ (lane & 7)) << 4;   // k-slice s=0
    const int chunk1 = ((laneHi + 4) ^ (lane & 7)) << 4;   // k-slice s=1
    const int aLane = (wm * 64 + lane15) * 128;            // within A (+mh*16384 +i*2048)
    const int bLane = 32768 + (wn * 32 + lane15) * 128;    // within B (+nh*16384 +jf*2048)

    floatx4 acc00[4][2] = {}, acc01[4][2] = {}, acc11[4][2] = {}, acc10[4][2] = {};
    bf16x8 a[4][2], b0[2][2], b1[2][2];

    // ---- prologue: stage tile0 fully + tile1 regions 0..2 (7 half-tiles),
    //      drain the 8 oldest (= all of tile0) ----
    STAGE(0, 0); STAGE(0, 1); STAGE(0, 2); STAGE(0, 3);
    STAGE(1, 0); STAGE(1, 1); STAGE(1, 2);
    asm volatile("s_waitcnt vmcnt(6)" ::: "memory");
    SBAR(); __builtin_amdgcn_s_barrier(); SBAR();

#pragma unroll 2
    for (int t = 0; t < NT; ++t) {
        const char* sA = smem + ((t & 1) << 16) + aLane;
        const char* sB = smem + ((t & 1) << 16) + bLane;

        // -------- phase 0: quadrant (mh=0, nh=0); stage B-hi of t+1 --------
#pragma unroll
        for (int i = 0; i < 4; ++i) {
            a[i][0] = *(const bf16x8*)(sA + i * 2048 + chunk0);
            a[i][1] = *(const bf16x8*)(sA + i * 2048 + chunk1);
        }
#pragma unroll
        for (int j = 0; j < 2; ++j) {
            b0[j][0] = *(const bf16x8*)(sB + j * 2048 + chunk0);
            b0[j][1] = *(const bf16x8*)(sB + j * 2048 + chunk1);
        }
        STAGE(t + 1, 3);
        SBAR(); __builtin_amdgcn_s_barrier(); SBAR();
        __builtin_amdgcn_s_setprio(1);
#pragma unroll
        for (int i = 0; i < 4; ++i)
#pragma unroll
            for (int j = 0; j < 2; ++j) {
                acc00[i][j] = __builtin_amdgcn_mfma_f32_16x16x32_bf16(a[i][0], b0[j][0], acc00[i][j], 0, 0, 0);
                acc00[i][j] = __builtin_amdgcn_mfma_f32_16x16x32_bf16(a[i][1], b0[j][1], acc00[i][j], 0, 0, 0);
            }
        __builtin_amdgcn_s_setprio(0);
        SBAR(); __builtin_amdgcn_s_barrier(); SBAR();

        // -------- phase 1: quadrant (0,1); stage A-lo of t+2 --------
#pragma unroll
        for (int j = 0; j < 2; ++j) {
            b1[j][0] = *(const bf16x8*)(sB + 16384 + j * 2048 + chunk0);
            b1[j][1] = *(const bf16x8*)(sB + 16384 + j * 2048 + chunk1);
        }
        STAGE(t + 2, 0);
        SBAR(); __builtin_amdgcn_s_barrier(); SBAR();
        __builtin_amdgcn_s_setprio(1);
#pragma unroll
        for (int i = 0; i < 4; ++i)
#pragma unroll
            for (int j = 0; j < 2; ++j) {
                acc01[i][j] = __builtin_amdgcn_mfma_f32_16x16x32_bf16(a[i][0], b1[j][0], acc01[i][j], 0, 0, 0);
                acc01[i][j] = __builtin_amdgcn_mfma_f32_16x16x32_bf16(a[i][1], b1[j][1], acc01[i][j], 0, 0, 0);
            }
        __builtin_amdgcn_s_setprio(0);
        SBAR(); __builtin_amdgcn_s_barrier(); SBAR();

        // -------- phase 2: quadrant (1,1); stage B-lo of t+2 --------
#pragma unroll
        for (int i = 0; i < 4; ++i) {
            a[i][0] = *(const bf16x8*)(sA + 16384 + i * 2048 + chunk0);
            a[i][1] = *(const bf16x8*)(sA + 16384 + i * 2048 + chunk1);
        }
        STAGE(t + 2, 1);
        SBAR(); __builtin_amdgcn_s_barrier(); SBAR();
        __builtin_amdgcn_s_setprio(1);
#pragma unroll
        for (int i = 0; i < 4; ++i)
#pragma unroll
            for (int j = 0; j < 2; ++j) {
                acc11[i][j] = __builtin_amdgcn_mfma_f32_16x16x32_bf16(a[i][0], b1[j][0], acc11[i][j], 0, 0, 0);
                acc11[i][j] = __builtin_amdgcn_mfma_f32_16x16x32_bf16(a[i][1], b1[j][1], acc11[i][j], 0, 0, 0);
            }
        __builtin_amdgcn_s_setprio(0);
        SBAR(); __builtin_amdgcn_s_barrier(); SBAR();

        // -------- phase 3: quadrant (1,0); stage A-hi of t+2; tile-boundary drain --------
        STAGE(t + 2, 2);
        SBAR(); __builtin_amdgcn_s_barrier(); SBAR();
        __builtin_amdgcn_s_setprio(1);
#pragma unroll
        for (int i = 0; i < 4; ++i)
#pragma unroll
            for (int j = 0; j < 2; ++j) {
                acc10[i][j] = __builtin_amdgcn_mfma_f32_16x16x32_bf16(a[i][0], b0[j][0], acc10[i][j], 0, 0, 0);
                acc10[i][j] = __builtin_amdgcn_mfma_f32_16x16x32_bf16(a[i][1], b0[j][1], acc10[i][j], 0, 0, 0);
            }
        __builtin_amdgcn_s_setprio(0);
        SBAR();
        // steady state: 14 outstanding, drain 8 oldest (= all of tile t+1).
        // tail (t+2 >= NT): the t+2 stages were skipped -> drain fully.
        if (t + 2 < NT) {
            asm volatile("s_waitcnt vmcnt(6)" ::: "memory");
        } else {
            asm volatile("s_waitcnt vmcnt(0)" ::: "memory");
        }
        __builtin_amdgcn_s_barrier(); SBAR();
    }
#undef STAGE

    // ---- epilogue ----
    const int erow = bm + wm * 64 + (laneHi << 2);
    const int ecol = bn + wn * 32 + lane15;
#define EPI(ACC, MH, NH)                                                            \
    _Pragma("unroll")                                                               \
    for (int i = 0; i < 4; ++i) {                                                   \
        _Pragma("unroll")                                                           \
        for (int jf = 0; jf < 2; ++jf) {                                            \
            const int c = ecol + (NH) * 128 + jf * 16;                              \
            _Pragma("unroll")                                                       \
            for (int j = 0; j < 4; ++j) {                                           \
                const int r = erow + (MH) * 128 + i * 16 + j;                       \
                const size_t idx = (size_t)r * N + c;                               \
                const float val = ACC[i][jf][j];                                    \
                if (MODE == GM_BF16) {                                              \
                    ((__hip_bfloat16*)outv)[idx] = f2bf(val);                       \
                } else if (MODE == GM_ADDX) {                                       \
                    ((float*)outv)[idx] = auxf[idx] + bias[c] + val;                \
                } else if (MODE == GM_SIG) {                                        \
                    ((__hip_bfloat16*)outv)[idx] = f2bf(1.f / (1.f + __expf(-val))); \
                } else if (MODE == GM_RELU2) {                                      \
                    float tp = fmaxf(val, 0.f);                                     \
                    ((__hip_bfloat16*)outv)[idx] = f2bf(tp * tp);                   \
                } else {                                                            \
                    float* o = (float*)outv;                                        \
                    o[idx] = o[idx] + bf2f(auxb[idx]) * val;                        \
                }                                                                   \
            }                                                                       \
        }                                                                           \
    }
    EPI(acc00, 0, 0)
    EPI(acc01, 0, 1)
    EPI(acc11, 1, 1)
    EPI(acc10, 1, 0)
#undef EPI
}

// ---------------- launch ----------------
extern "C" void kernel_launch(void* const* d_in, const int* in_sizes, int n_in,
                              void* d_out, int out_size, void* d_ws, size_t ws_size,
                              hipStream_t stream) {
    const float* x      = (const float*)d_in[0];
    const float* ln1_w  = (const float*)d_in[1];
    const float* ln1_b  = (const float*)d_in[2];
    const float* ln2_w  = (const float*)d_in[3];
    const float* ln2_b  = (const float*)d_in[4];
    const float* tm_u   = (const float*)d_in[5];
    const float* tm_w   = (const float*)d_in[6];
    const float* tm_mk  = (const float*)d_in[7];
    const float* tm_mv  = (const float*)d_in[8];
    const float* tm_mr  = (const float*)d_in[9];
    const float* tm_bo  = (const float*)d_in[14];
    const float* cm_mk  = (const float*)d_in[15];
    const float* cm_mr  = (const float*)d_in[16];

    const int D = in_sizes[1];           // 2048
    const int Mrows = in_sizes[0] / D;   // 16384
    const int T = 2048;
    const int Bb = Mrows / T;            // 8
    const size_t dd = (size_t)D * D;
    const size_t md = (size_t)Mrows * D;
    const int nch = T / WKV_CH;          // 32

    __hip_bfloat16* W = (__hip_bfloat16*)d_ws;
    __hip_bfloat16* buf[7];
    for (int i = 0; i < 7; ++i) buf[i] = W + 7 * dd + (size_t)i * md;
    // buf0: xln -> (scan scratch) -> x2ln ; buf1: xk -> xk2 ; buf2: xv -> xr2
    // buf3: xr -> r2s ; buf4: k ; buf5: v -> wkv*r ; buf6: r -> k2

    float* S = (float*)buf[0];
    const size_t cs = (size_t)Bb * nch * D;   // 524288 floats = 2 MB
    float* Ac  = S;
    float* Bc  = S + cs;
    float* Pc  = S + 2 * cs;
    float* Ain = S + 3 * cs;
    float* Bin = S + 4 * cs;

    const int widx[7] = {10, 11, 12, 13, 17, 18, 19};
    for (int i = 0; i < 7; ++i)
        k_f2bf<<<(int)(dd / 256), 256, 0, stream>>>((const float*)d_in[widx[i]], W + (size_t)i * dd, (int)dd);

    k_ln<<<Mrows, 256, 0, stream>>>(x, ln1_w, ln1_b, buf[0], D);
    k_tmix<<<dim3(D / 256, Mrows), 256, 0, stream>>>(buf[0], tm_mk, tm_mv, tm_mr,
                                                     buf[1], buf[2], buf[3], T, D);
    dim3 gg(D / 256, Mrows / 256);
    gemm_bt<GM_BF16><<<gg, 512, 0, stream>>>(buf[1], W + 0 * dd, buf[4], nullptr, nullptr, nullptr, D, D);
    gemm_bt<GM_BF16><<<gg, 512, 0, stream>>>(buf[2], W + 1 * dd, buf[5], nullptr, nullptr, nullptr, D, D);
    gemm_bt<GM_BF16><<<gg, 512, 0, stream>>>(buf[3], W + 2 * dd, buf[6], nullptr, nullptr, nullptr, D, D);

    k_wkv_p1<<<(Bb * D * nch) / 256, 256, 0, stream>>>(buf[4], buf[5], tm_u, tm_w,
                                                       Ac, Bc, Pc, T, D, nch);
    k_wkv_p2<<<(Bb * D) / 256, 256, 0, stream>>>(Ac, Bc, Pc, Ain, Bin, D, nch);
    k_wkv_p3<<<(Bb * D * nch) / 256, 256, 0, stream>>>(buf[4], buf[5], buf[6], tm_u, tm_w,
                                                       Ain, Bin, buf[5], T, D, nch);

    gemm_bt<GM_ADDX><<<gg, 512, 0, stream>>>(buf[5], W + 3 * dd, d_out, x, tm_bo, nullptr, D, D);
    k_ln<<<Mrows, 256, 0, stream>>>((const float*)d_out, ln2_w, ln2_b, buf[0], D);
    k_cmix<<<dim3(D / 256, Mrows), 256, 0, stream>>>(buf[0], cm_mk, cm_mr, buf[1], buf[2], T, D);
    gemm_bt<GM_SIG><<<gg, 512, 0, stream>>>(buf[2], W + 6 * dd, buf[3], nullptr, nullptr, nullptr, D, D);
    gemm_bt<GM_RELU2><<<gg, 512, 0, stream>>>(buf[1], W + 4 * dd, buf[6], nullptr, nullptr, nullptr, D, D);
    gemm_bt<GM_FINAL><<<gg, 512, 0, stream>>>(buf[6], W + 5 * dd, d_out, nullptr, nullptr, buf[3], D, D);
}